// Round 9
// baseline (206.013 us; speedup 1.0000x reference)
//
#include <hip/hip_runtime.h>
#include <hip/hip_bf16.h>
#include <type_traits>

#define D 64
#define KPER 20

typedef __attribute__((ext_vector_type(8))) short short8;
typedef __attribute__((ext_vector_type(4))) float floatx4;

__device__ __forceinline__ unsigned short f2bfu(float x) {
    __hip_bfloat16 h = __float2bfloat16(x);
    return *reinterpret_cast<unsigned short*>(&h);
}
__device__ __forceinline__ float bfu2f(unsigned short u) {
    return __uint_as_float(((unsigned)u) << 16);
}

__device__ __forceinline__ float fast_tanh(float x) {
    float xc = fminf(fmaxf(x, -15.f), 15.f);
    float e = __expf(2.f * xc);
    return 1.f - 2.f * __builtin_amdgcn_rcpf(1.f + e);
}

// ---- DPP 64-lane reductions (VALU pipe, no DS) -------------------------
template<int CTRL>
__device__ __forceinline__ float dpp_add(float x) {
    int t = __builtin_amdgcn_update_dpp(0, __float_as_int(x), CTRL, 0xf, 0xf, true);
    return x + __int_as_float(t);
}
template<int CTRL>
__device__ __forceinline__ float dpp_max(float x) {
    int xi = __float_as_int(x);
    int t = __builtin_amdgcn_update_dpp(xi, xi, CTRL, 0xf, 0xf, false);
    return fmaxf(x, __int_as_float(t));
}
__device__ __forceinline__ float wave_sum_b(float x) {
    x = dpp_add<0x111>(x); x = dpp_add<0x112>(x);
    x = dpp_add<0x114>(x); x = dpp_add<0x118>(x);
    x = dpp_add<0x142>(x); x = dpp_add<0x143>(x);
    return __int_as_float(__builtin_amdgcn_readlane(__float_as_int(x), 63));
}
__device__ __forceinline__ float wave_max_b(float x) {
    x = dpp_max<0x111>(x); x = dpp_max<0x112>(x);
    x = dpp_max<0x114>(x); x = dpp_max<0x118>(x);
    x = dpp_max<0x142>(x); x = dpp_max<0x143>(x);
    return __int_as_float(__builtin_amdgcn_readlane(__float_as_int(x), 63));
}

// ---- compile-time unroll helper ---------------------------------------
template<int I, int N, typename F>
__device__ __forceinline__ void static_for(F&& f) {
    if constexpr (I < N) {
        f(std::integral_constant<int, I>{});
        static_for<I + 1, N>(f);
    }
}

// pick metadata slot (compile-time) from the 3 cooperative regs -> SGPR
template<int SLOT>
__device__ __forceinline__ int get_slot(int m0, int m1, int m2) {
    if constexpr (SLOT < 64)       return __builtin_amdgcn_readlane(m0, SLOT);
    else if constexpr (SLOT < 128) return __builtin_amdgcn_readlane(m1, SLOT - 64);
    else                           return __builtin_amdgcn_readlane(m2, SLOT - 128);
}

// ---- K=64 projection, pair of row-tiles per wave, all A-loads up front -
__device__ __forceinline__ void proj64_pair(const float* __restrict__ h,
        const float* __restrict__ W, const float* __restrict__ b,
        unsigned short* __restrict__ out, int rt0) {
    constexpr int K = 64, KT = 2, CTN = 4;
    int lane = threadIdx.x & 63;
    int m = lane & 15, quad = lane >> 4;
    short8 bfr[CTN][KT];
    #pragma unroll
    for (int ct = 0; ct < CTN; ++ct)
        #pragma unroll
        for (int kt = 0; kt < KT; ++kt)
            #pragma unroll
            for (int j = 0; j < 8; ++j)
                bfr[ct][kt][j] = (short)f2bfu(W[(size_t)(kt * 32 + quad * 8 + j) * 64 + ct * 16 + m]);
    float bv[CTN];
    #pragma unroll
    for (int ct = 0; ct < CTN; ++ct) bv[ct] = b[ct * 16 + m];
    int rt1 = rt0 + 1;
    const float* hrow0 = h + (size_t)(rt0 * 16 + m) * K + quad * 8;
    const float* hrow1 = h + (size_t)(rt1 * 16 + m) * K + quad * 8;
    floatx4 a0[KT][2], a1[KT][2];
    #pragma unroll
    for (int kt = 0; kt < KT; ++kt) {
        a0[kt][0] = *(const floatx4*)(hrow0 + kt * 32);
        a0[kt][1] = *(const floatx4*)(hrow0 + kt * 32 + 4);
        a1[kt][0] = *(const floatx4*)(hrow1 + kt * 32);
        a1[kt][1] = *(const floatx4*)(hrow1 + kt * 32 + 4);
    }
    #pragma unroll
    for (int t = 0; t < 2; ++t) {
        floatx4 (*ar)[2] = t ? a1 : a0;
        int rt = t ? rt1 : rt0;
        floatx4 acc[CTN];
        #pragma unroll
        for (int ct = 0; ct < CTN; ++ct) acc[ct] = floatx4{0.f, 0.f, 0.f, 0.f};
        #pragma unroll
        for (int kt = 0; kt < KT; ++kt) {
            short8 af;
            #pragma unroll
            for (int j = 0; j < 4; ++j) {
                af[j]     = (short)f2bfu(ar[kt][0][j]);
                af[j + 4] = (short)f2bfu(ar[kt][1][j]);
            }
            #pragma unroll
            for (int ct = 0; ct < CTN; ++ct)
                acc[ct] = __builtin_amdgcn_mfma_f32_16x16x32_bf16(af, bfr[ct][kt], acc[ct], 0, 0, 0);
        }
        #pragma unroll
        for (int ct = 0; ct < CTN; ++ct) {
            int col = ct * 16 + m;
            #pragma unroll
            for (int reg = 0; reg < 4; ++reg) {
                int row = rt * 16 + quad * 4 + reg;
                out[(size_t)row * 64 + col] = f2bfu(fast_tanh(acc[ct][reg] + bv[ct]));
            }
        }
    }
}

// ---- K=256 projection body (loop, CTN=2 halves) ------------------------
__device__ __forceinline__ void proj256_body(const float* __restrict__ h,
        const float* __restrict__ W, const float* __restrict__ b,
        unsigned short* __restrict__ out, int ct0, int rt0, int rtstride, int ntiles) {
    constexpr int K = 256, KT = 8, CTN = 2;
    int lane = threadIdx.x & 63;
    int m = lane & 15, quad = lane >> 4;
    short8 bfr[CTN][KT];
    #pragma unroll
    for (int ct = 0; ct < CTN; ++ct)
        #pragma unroll
        for (int kt = 0; kt < KT; ++kt)
            #pragma unroll
            for (int j = 0; j < 8; ++j)
                bfr[ct][kt][j] = (short)f2bfu(W[(size_t)(kt * 32 + quad * 8 + j) * 64 + (ct0 + ct) * 16 + m]);
    float bv[CTN];
    #pragma unroll
    for (int ct = 0; ct < CTN; ++ct) bv[ct] = b[(ct0 + ct) * 16 + m];
    for (int rt = rt0; rt < ntiles; rt += rtstride) {
        floatx4 acc[CTN];
        #pragma unroll
        for (int ct = 0; ct < CTN; ++ct) acc[ct] = floatx4{0.f, 0.f, 0.f, 0.f};
        const float* hrow = h + (size_t)(rt * 16 + m) * K + quad * 8;
        #pragma unroll
        for (int kt = 0; kt < KT; ++kt) {
            floatx4 v0 = *(const floatx4*)(hrow + kt * 32);
            floatx4 v1 = *(const floatx4*)(hrow + kt * 32 + 4);
            short8 af;
            #pragma unroll
            for (int j = 0; j < 4; ++j) {
                af[j]     = (short)f2bfu(v0[j]);
                af[j + 4] = (short)f2bfu(v1[j]);
            }
            #pragma unroll
            for (int ct = 0; ct < CTN; ++ct)
                acc[ct] = __builtin_amdgcn_mfma_f32_16x16x32_bf16(af, bfr[ct][kt], acc[ct], 0, 0, 0);
        }
        #pragma unroll
        for (int ct = 0; ct < CTN; ++ct) {
            int col = (ct0 + ct) * 16 + m;
            #pragma unroll
            for (int reg = 0; reg < 4; ++reg) {
                int row = rt * 16 + quad * 4 + reg;
                out[(size_t)row * 64 + col] = f2bfu(fast_tanh(acc[ct][reg] + bv[ct]));
            }
        }
    }
}

// Fused: [0,g64) K=64 tile-pairs; [g64,g64+g256) K=256 halves; next RELB
// blocks convert rel_table fp32->bf16; last ZB blocks zero d_out.
// (R6 config — measured-best proj; R7/R8 CTN=4 variant regressed: 256-load
//  B-init per wave amortized over ~1.5 tiles, occupancy 9%.)
#define RELB 16
#define ZB 8
__global__ __launch_bounds__(256) void proj_fused(
        const float* __restrict__ hcon, const float* __restrict__ Wc, const float* __restrict__ bc,
        const float* __restrict__ hun, const float* __restrict__ Wu, const float* __restrict__ bu,
        const float* __restrict__ relf, unsigned short* __restrict__ hc,
        unsigned short* __restrict__ hu, unsigned short* __restrict__ relb,
        float* __restrict__ outz, int nout,
        int t64, int t256, int g64, int g256, int nrel) {
    int bid = blockIdx.x;
    int w = threadIdx.x >> 6;
    if (bid < g64) {
        int wid = bid * 4 + w;              // [0, t64/2)
        proj64_pair(hcon, Wc, bc, hc, wid * 2);
    } else if (bid < g64 + g256) {
        int wid = (bid - g64) * 4 + w;
        int half = wid & 1;                 // fixed per wave -> B-frags loaded once
        proj256_body(hun, Wu, bu, hu, half * 2, wid >> 1, (g256 * 4) >> 1, t256);
    } else if (bid < g64 + g256 + RELB) {
        int tid = (bid - g64 - g256) * 256 + threadIdx.x;
        for (int i = tid; i < nrel; i += RELB * 256) relb[i] = f2bfu(relf[i]);
    } else {
        int tid = (bid - g64 - g256 - RELB) * 256 + threadIdx.x;
        for (int i = tid; i < nout; i += ZB * 256) outz[i] = 0.0f;
    }
}

// One wave per sorted vi-segment (KPER consecutive edges). Metadata via
// cooperative vector load + v_readlane -> SGPR. ALL 80 feature gathers
// issued up front into flat arrays (compiler keeps SSA scheduling freedom;
// rotating-slot hand-pipelining regressed in R6). [R8 structure, measured
// best: 45.7 µs, VALUBusy 64%]
__global__ __launch_bounds__(256) void edge_kernel(
        const float* __restrict__ natt, const int* __restrict__ edges,
        const float* __restrict__ ey, const unsigned short* __restrict__ hc,
        const unsigned short* __restrict__ hu, const unsigned short* __restrict__ relt,
        const float* __restrict__ wsm, const float* __restrict__ fb,
        const float* __restrict__ outw, float* __restrict__ out, int N) {
    int lane = threadIdx.x & 63;
    int s = blockIdx.x * 4 + (threadIdx.x >> 6);
    long base = (long)s * KPER;
    const int* eb = edges + base * 8;          // 160 ints of segment metadata
    int m0 = eb[lane];
    int m1 = eb[64 + lane];
    int m2 = (lane < 32) ? eb[128 + lane] : 0; // guard: segment metadata is 160 ints
    int eg = get_slot<0>(m0, m1, m2);
    int vi = get_slot<1>(m0, m1, m2);
    float f1 = bfu2f(hu[(size_t)vi * D + lane]);
    float na = natt[(size_t)eg * N + vi];      // uniform -> s_load

    // issue all gathers first
    unsigned short F0r[KPER], F2r[KPER], F3r[KPER], F4r[KPER];
    int vjr[KPER];
    static_for<0, KPER>([&](auto ec) {
        constexpr int e = decltype(ec)::value;
        int vj  = get_slot<e * 8 + 2>(m0, m1, m2);
        int rel = get_slot<e * 8 + 3>(m0, m1, m2);
        int evi = get_slot<e * 8 + 6>(m0, m1, m2);
        int evj = get_slot<e * 8 + 7>(m0, m1, m2);
        F0r[e] = hc[(size_t)evi * D + lane];
        F2r[e] = relt[(size_t)rel * D + lane];
        F3r[e] = hc[(size_t)evj * D + lane];
        F4r[e] = hu[(size_t)vj * D + lane];
        vjr[e] = vj;
    });

    float w0 = wsm[0 * D + lane], w1 = wsm[1 * D + lane];
    float w2 = wsm[2 * D + lane], w3 = wsm[3 * D + lane];
    float w4 = wsm[4 * D + lane], w5 = wsm[5 * D + lane];
    float w6 = wsm[6 * D + lane], w7 = wsm[7 * D + lane];
    float fbv = fb[lane], owv = outw[lane];
    float myl = -INFINITY;
    int myvj = 0;
    static_for<0, KPER>([&](auto ec) {
        constexpr int e = decltype(ec)::value;
        float F0 = bfu2f(F0r[e]);
        float F2 = bfu2f(F2r[e]);
        float F3 = bfu2f(F3r[e]);
        float F4 = bfu2f(F4r[e]);
        float t1 = fmaf(F2, w1, w0);
        float t2 = fmaf(F2, w5, w4);
        float t3 = fmaf(F2, w3, w2);
        float t4 = fmaf(F2, w7, w6);
        float u = fmaf(F0, t1, f1 * t2);
        float v = fmaf(F0, t3, f1 * t4);
        float o = fmaf(F3, u, fmaf(F4, v, fbv));
        o = fmaxf(o, 0.0f) * owv;    // relu(out)*out_w ; out_b cancels in softmax
        float tot = wave_sum_b(o);   // DPP reduce, VALU pipe
        bool mine = (lane == e);
        myl = mine ? tot : myl;
        myvj = mine ? vjr[e] : myvj;
    });
    float mx = wave_max_b(myl);
    float ex = __expf(myl - mx);     // lanes >= KPER hold -inf -> ex = 0
    float den = wave_sum_b(ex);
    if (lane < KPER) {
        float t = (ex / den) * na * ey[base + lane];
        atomicAdd(out + (size_t)eg * N + myvj, t);
    }
}

extern "C" void kernel_launch(void* const* d_in, const int* in_sizes, int n_in,
                              void* d_out, int out_size, void* d_ws, size_t ws_size,
                              hipStream_t stream) {
    const float* natt = (const float*)d_in[0];
    const int*   edges = (const int*)d_in[1];
    const float* ey   = (const float*)d_in[2];
    const float* hun  = (const float*)d_in[3];
    const float* hcon = (const float*)d_in[4];
    const float* Wc   = (const float*)d_in[5];
    const float* bc   = (const float*)d_in[6];
    const float* Wu   = (const float*)d_in[7];
    const float* bu   = (const float*)d_in[8];
    const float* relt = (const float*)d_in[9];
    const float* wsm  = (const float*)d_in[10];
    const float* fb   = (const float*)d_in[11];
    const float* outw = (const float*)d_in[12];
    float* out = (float*)d_out;

    int E    = in_sizes[2];          // 400000 edges
    int S    = E / KPER;             // 20000 sorted vi segments
    int nmem = in_sizes[4] / D;      // 131072 hidden_con rows
    int N    = in_sizes[3] / 256;    // 50000 nodes
    int nrel = in_sizes[9];          // 500*64

    int t64  = nmem / 16;            // 8192 row-tiles
    int t256 = N / 16;               // 3125 row-tiles
    int g64  = t64 / 8;              // 1024 blocks: 4 waves x 2 tiles each
    int g256 = 512;

    unsigned short* hc = (unsigned short*)d_ws;
    unsigned short* hu = hc + (size_t)nmem * D;
    unsigned short* rb = hu + (size_t)N * D;

    proj_fused<<<g64 + g256 + RELB + ZB, 256, 0, stream>>>(hcon, Wc, bc, hun, Wu, bu,
                                                           relt, hc, hu, rb,
                                                           out, out_size,
                                                           t64, t256, g64, g256, nrel);
    edge_kernel<<<S / 4, 256, 0, stream>>>(natt, edges, ey, hc, hu, rb,
                                           wsm, fb, outw, out, N);
}

// Round 10
// 203.550 us; speedup vs baseline: 1.0121x; 1.0121x over previous
//
#include <hip/hip_runtime.h>
#include <hip/hip_bf16.h>
#include <type_traits>

#define D 64
#define KPER 20

typedef __attribute__((ext_vector_type(8))) short short8;
typedef __attribute__((ext_vector_type(4))) float floatx4;

__device__ __forceinline__ unsigned short f2bfu(float x) {
    __hip_bfloat16 h = __float2bfloat16(x);
    return *reinterpret_cast<unsigned short*>(&h);
}
__device__ __forceinline__ float bfu2f(unsigned short u) {
    return __uint_as_float(((unsigned)u) << 16);
}

__device__ __forceinline__ float fast_tanh(float x) {
    float xc = fminf(fmaxf(x, -15.f), 15.f);
    float e = __expf(2.f * xc);
    return 1.f - 2.f * __builtin_amdgcn_rcpf(1.f + e);
}

// ---- DPP reductions (VALU pipe) ----------------------------------------
template<int CTRL>
__device__ __forceinline__ float dpp_add(float x) {
    int t = __builtin_amdgcn_update_dpp(0, __float_as_int(x), CTRL, 0xf, 0xf, true);
    return x + __int_as_float(t);
}
template<int CTRL>
__device__ __forceinline__ float dpp_max(float x) {
    int xi = __float_as_int(x);
    int t = __builtin_amdgcn_update_dpp(xi, xi, CTRL, 0xf, 0xf, false);
    return fmaxf(x, __int_as_float(t));
}
__device__ __forceinline__ float wave_sum_b(float x) {
    x = dpp_add<0x111>(x); x = dpp_add<0x112>(x);
    x = dpp_add<0x114>(x); x = dpp_add<0x118>(x);
    x = dpp_add<0x142>(x); x = dpp_add<0x143>(x);
    return __int_as_float(__builtin_amdgcn_readlane(__float_as_int(x), 63));
}
__device__ __forceinline__ float wave_max_b(float x) {
    x = dpp_max<0x111>(x); x = dpp_max<0x112>(x);
    x = dpp_max<0x114>(x); x = dpp_max<0x118>(x);
    x = dpp_max<0x142>(x); x = dpp_max<0x143>(x);
    return __int_as_float(__builtin_amdgcn_readlane(__float_as_int(x), 63));
}
// 16-lane (row) inclusive sum: after shr 1,2,4,8 lane 15 of each row holds the row total
__device__ __forceinline__ float row16_sum(float x) {
    x = dpp_add<0x111>(x); x = dpp_add<0x112>(x);
    x = dpp_add<0x114>(x); x = dpp_add<0x118>(x);
    return x;
}

// ---- K=64 projection, pair of row-tiles per wave, all A-loads up front -
__device__ __forceinline__ void proj64_pair(const float* __restrict__ h,
        const float* __restrict__ W, const float* __restrict__ b,
        unsigned short* __restrict__ out, int rt0) {
    constexpr int K = 64, KT = 2, CTN = 4;
    int lane = threadIdx.x & 63;
    int m = lane & 15, quad = lane >> 4;
    short8 bfr[CTN][KT];
    #pragma unroll
    for (int ct = 0; ct < CTN; ++ct)
        #pragma unroll
        for (int kt = 0; kt < KT; ++kt)
            #pragma unroll
            for (int j = 0; j < 8; ++j)
                bfr[ct][kt][j] = (short)f2bfu(W[(size_t)(kt * 32 + quad * 8 + j) * 64 + ct * 16 + m]);
    float bv[CTN];
    #pragma unroll
    for (int ct = 0; ct < CTN; ++ct) bv[ct] = b[ct * 16 + m];
    int rt1 = rt0 + 1;
    const float* hrow0 = h + (size_t)(rt0 * 16 + m) * K + quad * 8;
    const float* hrow1 = h + (size_t)(rt1 * 16 + m) * K + quad * 8;
    floatx4 a0[KT][2], a1[KT][2];
    #pragma unroll
    for (int kt = 0; kt < KT; ++kt) {
        a0[kt][0] = *(const floatx4*)(hrow0 + kt * 32);
        a0[kt][1] = *(const floatx4*)(hrow0 + kt * 32 + 4);
        a1[kt][0] = *(const floatx4*)(hrow1 + kt * 32);
        a1[kt][1] = *(const floatx4*)(hrow1 + kt * 32 + 4);
    }
    #pragma unroll
    for (int t = 0; t < 2; ++t) {
        floatx4 (*ar)[2] = t ? a1 : a0;
        int rt = t ? rt1 : rt0;
        floatx4 acc[CTN];
        #pragma unroll
        for (int ct = 0; ct < CTN; ++ct) acc[ct] = floatx4{0.f, 0.f, 0.f, 0.f};
        #pragma unroll
        for (int kt = 0; kt < KT; ++kt) {
            short8 af;
            #pragma unroll
            for (int j = 0; j < 4; ++j) {
                af[j]     = (short)f2bfu(ar[kt][0][j]);
                af[j + 4] = (short)f2bfu(ar[kt][1][j]);
            }
            #pragma unroll
            for (int ct = 0; ct < CTN; ++ct)
                acc[ct] = __builtin_amdgcn_mfma_f32_16x16x32_bf16(af, bfr[ct][kt], acc[ct], 0, 0, 0);
        }
        #pragma unroll
        for (int ct = 0; ct < CTN; ++ct) {
            int col = ct * 16 + m;
            #pragma unroll
            for (int reg = 0; reg < 4; ++reg) {
                int row = rt * 16 + quad * 4 + reg;
                out[(size_t)row * 64 + col] = f2bfu(fast_tanh(acc[ct][reg] + bv[ct]));
            }
        }
    }
}

// ---- K=256 projection body (loop, CTN=2 halves) ------------------------
__device__ __forceinline__ void proj256_body(const float* __restrict__ h,
        const float* __restrict__ W, const float* __restrict__ b,
        unsigned short* __restrict__ out, int ct0, int rt0, int rtstride, int ntiles) {
    constexpr int K = 256, KT = 8, CTN = 2;
    int lane = threadIdx.x & 63;
    int m = lane & 15, quad = lane >> 4;
    short8 bfr[CTN][KT];
    #pragma unroll
    for (int ct = 0; ct < CTN; ++ct)
        #pragma unroll
        for (int kt = 0; kt < KT; ++kt)
            #pragma unroll
            for (int j = 0; j < 8; ++j)
                bfr[ct][kt][j] = (short)f2bfu(W[(size_t)(kt * 32 + quad * 8 + j) * 64 + (ct0 + ct) * 16 + m]);
    float bv[CTN];
    #pragma unroll
    for (int ct = 0; ct < CTN; ++ct) bv[ct] = b[(ct0 + ct) * 16 + m];
    for (int rt = rt0; rt < ntiles; rt += rtstride) {
        floatx4 acc[CTN];
        #pragma unroll
        for (int ct = 0; ct < CTN; ++ct) acc[ct] = floatx4{0.f, 0.f, 0.f, 0.f};
        const float* hrow = h + (size_t)(rt * 16 + m) * K + quad * 8;
        #pragma unroll
        for (int kt = 0; kt < KT; ++kt) {
            floatx4 v0 = *(const floatx4*)(hrow + kt * 32);
            floatx4 v1 = *(const floatx4*)(hrow + kt * 32 + 4);
            short8 af;
            #pragma unroll
            for (int j = 0; j < 4; ++j) {
                af[j]     = (short)f2bfu(v0[j]);
                af[j + 4] = (short)f2bfu(v1[j]);
            }
            #pragma unroll
            for (int ct = 0; ct < CTN; ++ct)
                acc[ct] = __builtin_amdgcn_mfma_f32_16x16x32_bf16(af, bfr[ct][kt], acc[ct], 0, 0, 0);
        }
        #pragma unroll
        for (int ct = 0; ct < CTN; ++ct) {
            int col = (ct0 + ct) * 16 + m;
            #pragma unroll
            for (int reg = 0; reg < 4; ++reg) {
                int row = rt * 16 + quad * 4 + reg;
                out[(size_t)row * 64 + col] = f2bfu(fast_tanh(acc[ct][reg] + bv[ct]));
            }
        }
    }
}

// Fused proj (R9 config, unchanged for attribution).
#define RELB 16
#define ZB 8
__global__ __launch_bounds__(256) void proj_fused(
        const float* __restrict__ hcon, const float* __restrict__ Wc, const float* __restrict__ bc,
        const float* __restrict__ hun, const float* __restrict__ Wu, const float* __restrict__ bu,
        const float* __restrict__ relf, unsigned short* __restrict__ hc,
        unsigned short* __restrict__ hu, unsigned short* __restrict__ relb,
        float* __restrict__ outz, int nout,
        int t64, int t256, int g64, int g256, int nrel) {
    int bid = blockIdx.x;
    int w = threadIdx.x >> 6;
    if (bid < g64) {
        int wid = bid * 4 + w;
        proj64_pair(hcon, Wc, bc, hc, wid * 2);
    } else if (bid < g64 + g256) {
        int wid = (bid - g64) * 4 + w;
        int half = wid & 1;
        proj256_body(hun, Wu, bu, hu, half * 2, wid >> 1, (g256 * 4) >> 1, t256);
    } else if (bid < g64 + g256 + RELB) {
        int tid = (bid - g64 - g256) * 256 + threadIdx.x;
        for (int i = tid; i < nrel; i += RELB * 256) relb[i] = f2bfu(relf[i]);
    } else {
        int tid = (bid - g64 - g256 - RELB) * 256 + threadIdx.x;
        for (int i = tid; i < nout; i += ZB * 256) outz[i] = 0.0f;
    }
}

__device__ __forceinline__ void unp4(uint2 u, float f[4]) {
    f[0] = __uint_as_float(u.x << 16);
    f[1] = __uint_as_float(u.x & 0xffff0000u);
    f[2] = __uint_as_float(u.y << 16);
    f[3] = __uint_as_float(u.y & 0xffff0000u);
}

// One wave per sorted vi-segment. NEW layout: 4 edges x 16 lanes; each lane
// owns 4 features (ushort4 gathers = 8B loads, 4x fewer VMEM + addr ops).
// Per-4-edge reduction: 4 DPP row_shr adds within 16-lane rows + 1 shfl.
__global__ __launch_bounds__(256) void edge_kernel(
        const float* __restrict__ natt, const int* __restrict__ edges,
        const float* __restrict__ ey, const unsigned short* __restrict__ hc,
        const unsigned short* __restrict__ hu, const unsigned short* __restrict__ relt,
        const float* __restrict__ wsm, const float* __restrict__ fb,
        const float* __restrict__ outw, float* __restrict__ out, int N) {
    int lane = threadIdx.x & 63;
    int g = lane >> 4, sub = lane & 15;
    int l2 = lane >> 2;
    int s = blockIdx.x * 4 + (threadIdx.x >> 6);
    long base = (long)s * KPER;
    const int* eb = edges + base * 8;
    int eg = __builtin_amdgcn_readfirstlane(eb[0]);
    int vi = __builtin_amdgcn_readfirstlane(eb[1]);

    // index loads: group g handles edges i*4+g, i=0..4 (imm-offset loads)
    const int* ebg = eb + g * 8;
    int vjx[5], relx[5], evix[5], evjx[5];
    #pragma unroll
    for (int i = 0; i < 5; ++i) {
        vjx[i]  = ebg[i * 32 + 2];
        relx[i] = ebg[i * 32 + 3];
        evix[i] = ebg[i * 32 + 6];
        evjx[i] = ebg[i * 32 + 7];
    }
    // feature gathers: 8B per lane (features sub*4 .. sub*4+3)
    uint2 G0[5], G2[5], G3[5], G4[5];
    #pragma unroll
    for (int i = 0; i < 5; ++i) {
        G0[i] = *(const uint2*)(hc   + (size_t)evix[i] * D + sub * 4);
        G2[i] = *(const uint2*)(relt + (size_t)relx[i] * D + sub * 4);
        G3[i] = *(const uint2*)(hc   + (size_t)evjx[i] * D + sub * 4);
        G4[i] = *(const uint2*)(hu   + (size_t)vjx[i]  * D + sub * 4);
    }
    uint2 F1u = *(const uint2*)(hu + (size_t)vi * D + sub * 4);
    float f1[4];
    unp4(F1u, f1);

    floatx4 wv[8];
    #pragma unroll
    for (int k = 0; k < 8; ++k) wv[k] = *(const floatx4*)(wsm + k * D + sub * 4);
    floatx4 fbv = *(const floatx4*)(fb + sub * 4);
    floatx4 owv = *(const floatx4*)(outw + sub * 4);
    float na = natt[(size_t)eg * N + vi];

    float myl = -INFINITY;
    #pragma unroll
    for (int i = 0; i < 5; ++i) {
        float F0[4], F2[4], F3[4], F4[4];
        unp4(G0[i], F0); unp4(G2[i], F2); unp4(G3[i], F3); unp4(G4[i], F4);
        float acc = 0.f;
        #pragma unroll
        for (int j = 0; j < 4; ++j) {
            float t1 = fmaf(F2[j], wv[1][j], wv[0][j]);
            float t2 = fmaf(F2[j], wv[5][j], wv[4][j]);
            float t3 = fmaf(F2[j], wv[3][j], wv[2][j]);
            float t4 = fmaf(F2[j], wv[7][j], wv[6][j]);
            float u = fmaf(F0[j], t1, f1[j] * t2);
            float v = fmaf(F0[j], t3, f1[j] * t4);
            float od = fmaf(F3[j], u, fmaf(F4[j], v, fbv[j]));
            acc = fmaf(fmaxf(od, 0.f), owv[j], acc);   // relu(out)*out_w; out_b cancels
        }
        float rs = row16_sum(acc);                 // lane 15 of each row: row total
        float tot = __shfl(rs, ((lane & 3) << 4) + 15);  // group (lane&3)'s total
        myl = (l2 == i) ? tot : myl;               // lane e = i*4+(lane&3) owns edge e
    }
    float mx = wave_max_b(myl);
    float ex = __expf(myl - mx);                   // lanes >= KPER hold -inf -> ex = 0
    float den = wave_sum_b(ex);
    if (lane < KPER) {
        int myvj = eb[lane * 8 + 2];
        float t = (ex / den) * na * ey[base + lane];
        atomicAdd(out + (size_t)eg * N + myvj, t);
    }
}

extern "C" void kernel_launch(void* const* d_in, const int* in_sizes, int n_in,
                              void* d_out, int out_size, void* d_ws, size_t ws_size,
                              hipStream_t stream) {
    const float* natt = (const float*)d_in[0];
    const int*   edges = (const int*)d_in[1];
    const float* ey   = (const float*)d_in[2];
    const float* hun  = (const float*)d_in[3];
    const float* hcon = (const float*)d_in[4];
    const float* Wc   = (const float*)d_in[5];
    const float* bc   = (const float*)d_in[6];
    const float* Wu   = (const float*)d_in[7];
    const float* bu   = (const float*)d_in[8];
    const float* relt = (const float*)d_in[9];
    const float* wsm  = (const float*)d_in[10];
    const float* fb   = (const float*)d_in[11];
    const float* outw = (const float*)d_in[12];
    float* out = (float*)d_out;

    int E    = in_sizes[2];          // 400000 edges
    int S    = E / KPER;             // 20000 sorted vi segments
    int nmem = in_sizes[4] / D;      // 131072 hidden_con rows
    int N    = in_sizes[3] / 256;    // 50000 nodes
    int nrel = in_sizes[9];          // 500*64

    int t64  = nmem / 16;            // 8192 row-tiles
    int t256 = N / 16;               // 3125 row-tiles
    int g64  = t64 / 8;              // 1024 blocks: 4 waves x 2 tiles each
    int g256 = 512;

    unsigned short* hc = (unsigned short*)d_ws;
    unsigned short* hu = hc + (size_t)nmem * D;
    unsigned short* rb = hu + (size_t)N * D;

    proj_fused<<<g64 + g256 + RELB + ZB, 256, 0, stream>>>(hcon, Wc, bc, hun, Wu, bu,
                                                           relt, hc, hu, rb,
                                                           out, out_size,
                                                           t64, t256, g64, g256, nrel);
    edge_kernel<<<S / 4, 256, 0, stream>>>(natt, edges, ey, hc, hu, rb,
                                           wsm, fb, outw, out, N);
}

// Round 11
// 201.423 us; speedup vs baseline: 1.0228x; 1.0106x over previous
//
#include <hip/hip_runtime.h>
#include <hip/hip_bf16.h>
#include <type_traits>

#define D 64
#define KPER 20

typedef __attribute__((ext_vector_type(8))) short short8;
typedef __attribute__((ext_vector_type(4))) float floatx4;

__device__ __forceinline__ unsigned short f2bfu(float x) {
    __hip_bfloat16 h = __float2bfloat16(x);
    return *reinterpret_cast<unsigned short*>(&h);
}
__device__ __forceinline__ float bfu2f(unsigned short u) {
    return __uint_as_float(((unsigned)u) << 16);
}

__device__ __forceinline__ float fast_tanh(float x) {
    float xc = fminf(fmaxf(x, -15.f), 15.f);
    float e = __expf(2.f * xc);
    return 1.f - 2.f * __builtin_amdgcn_rcpf(1.f + e);
}

// ---- DPP reductions (VALU pipe) ----------------------------------------
template<int CTRL>
__device__ __forceinline__ float dpp_add(float x) {
    int t = __builtin_amdgcn_update_dpp(0, __float_as_int(x), CTRL, 0xf, 0xf, true);
    return x + __int_as_float(t);
}
template<int CTRL>
__device__ __forceinline__ float dpp_max(float x) {
    int xi = __float_as_int(x);
    int t = __builtin_amdgcn_update_dpp(xi, xi, CTRL, 0xf, 0xf, false);
    return fmaxf(x, __int_as_float(t));
}
__device__ __forceinline__ float wave_sum_b(float x) {
    x = dpp_add<0x111>(x); x = dpp_add<0x112>(x);
    x = dpp_add<0x114>(x); x = dpp_add<0x118>(x);
    x = dpp_add<0x142>(x); x = dpp_add<0x143>(x);
    return __int_as_float(__builtin_amdgcn_readlane(__float_as_int(x), 63));
}
__device__ __forceinline__ float wave_max_b(float x) {
    x = dpp_max<0x111>(x); x = dpp_max<0x112>(x);
    x = dpp_max<0x114>(x); x = dpp_max<0x118>(x);
    x = dpp_max<0x142>(x); x = dpp_max<0x143>(x);
    return __int_as_float(__builtin_amdgcn_readlane(__float_as_int(x), 63));
}
__device__ __forceinline__ float row16_sum(float x) {
    x = dpp_add<0x111>(x); x = dpp_add<0x112>(x);
    x = dpp_add<0x114>(x); x = dpp_add<0x118>(x);
    return x;
}

// ---- prep: repack W into fragment-major bf16, convert rel, zero out ----
// Wcp[((ct*2+kt)*64+lane)*8+j]  = bf16(Wc[(kt*32+(lane>>4)*8+j)*64 + ct*16+(lane&15)])
// Wup[((ct*8+kt)*64+lane)*8+j]  = bf16(Wu[(kt*32+(lane>>4)*8+j)*64 + ct*16+(lane&15)])
__global__ __launch_bounds__(256) void prep(
        const float* __restrict__ Wc, const float* __restrict__ Wu,
        const float* __restrict__ relf,
        unsigned short* __restrict__ Wcp, unsigned short* __restrict__ Wup,
        unsigned short* __restrict__ relb, float* __restrict__ outz,
        int nout, int nrel) {
    int tid = blockIdx.x * 256 + threadIdx.x;
    int nth = gridDim.x * 256;
    for (int i = tid; i < 4 * 2 * 64 * 8; i += nth) {
        int j = i & 7, lane = (i >> 3) & 63, f = i >> 9;
        int ct = f >> 1, kt = f & 1;
        int m = lane & 15, quad = lane >> 4;
        Wcp[i] = f2bfu(Wc[(kt * 32 + quad * 8 + j) * 64 + ct * 16 + m]);
    }
    for (int i = tid; i < 4 * 8 * 64 * 8; i += nth) {
        int j = i & 7, lane = (i >> 3) & 63, f = i >> 9;
        int ct = f >> 3, kt = f & 7;
        int m = lane & 15, quad = lane >> 4;
        Wup[i] = f2bfu(Wu[(kt * 32 + quad * 8 + j) * 64 + ct * 16 + m]);
    }
    for (int i = tid; i < nrel; i += nth) relb[i] = f2bfu(relf[i]);
    for (int i = tid; i < nout; i += nth) outz[i] = 0.0f;
}

// ---- K=64 projection, pair of row-tiles per wave; packed-W frag init ---
__device__ __forceinline__ void proj64_pair(const float* __restrict__ h,
        const unsigned short* __restrict__ Wp, const float* __restrict__ b,
        unsigned short* __restrict__ out, int rt0) {
    constexpr int K = 64, KT = 2, CTN = 4;
    int lane = threadIdx.x & 63;
    int m = lane & 15, quad = lane >> 4;
    short8 bfr[CTN][KT];
    #pragma unroll
    for (int ct = 0; ct < CTN; ++ct)
        #pragma unroll
        for (int kt = 0; kt < KT; ++kt)
            bfr[ct][kt] = *(const short8*)(Wp + (((ct * 2 + kt) * 64 + lane) << 3));
    float bv[CTN];
    #pragma unroll
    for (int ct = 0; ct < CTN; ++ct) bv[ct] = b[ct * 16 + m];
    int rt1 = rt0 + 1;
    const float* hrow0 = h + (size_t)(rt0 * 16 + m) * K + quad * 8;
    const float* hrow1 = h + (size_t)(rt1 * 16 + m) * K + quad * 8;
    floatx4 a0[KT][2], a1[KT][2];
    #pragma unroll
    for (int kt = 0; kt < KT; ++kt) {
        a0[kt][0] = *(const floatx4*)(hrow0 + kt * 32);
        a0[kt][1] = *(const floatx4*)(hrow0 + kt * 32 + 4);
        a1[kt][0] = *(const floatx4*)(hrow1 + kt * 32);
        a1[kt][1] = *(const floatx4*)(hrow1 + kt * 32 + 4);
    }
    #pragma unroll
    for (int t = 0; t < 2; ++t) {
        floatx4 (*ar)[2] = t ? a1 : a0;
        int rt = t ? rt1 : rt0;
        floatx4 acc[CTN];
        #pragma unroll
        for (int ct = 0; ct < CTN; ++ct) acc[ct] = floatx4{0.f, 0.f, 0.f, 0.f};
        #pragma unroll
        for (int kt = 0; kt < KT; ++kt) {
            short8 af;
            #pragma unroll
            for (int j = 0; j < 4; ++j) {
                af[j]     = (short)f2bfu(ar[kt][0][j]);
                af[j + 4] = (short)f2bfu(ar[kt][1][j]);
            }
            #pragma unroll
            for (int ct = 0; ct < CTN; ++ct)
                acc[ct] = __builtin_amdgcn_mfma_f32_16x16x32_bf16(af, bfr[ct][kt], acc[ct], 0, 0, 0);
        }
        #pragma unroll
        for (int ct = 0; ct < CTN; ++ct) {
            int col = ct * 16 + m;
            #pragma unroll
            for (int reg = 0; reg < 4; ++reg) {
                int row = rt * 16 + quad * 4 + reg;
                out[(size_t)row * 64 + col] = f2bfu(fast_tanh(acc[ct][reg] + bv[ct]));
            }
        }
    }
}

// ---- K=256 projection (CTN=2 column-halves); packed-W frag init --------
__device__ __forceinline__ void proj256_body(const float* __restrict__ h,
        const unsigned short* __restrict__ Wp, const float* __restrict__ b,
        unsigned short* __restrict__ out, int ct0, int rt0, int rtstride, int ntiles) {
    constexpr int K = 256, KT = 8, CTN = 2;
    int lane = threadIdx.x & 63;
    int m = lane & 15, quad = lane >> 4;
    short8 bfr[CTN][KT];
    #pragma unroll
    for (int ct = 0; ct < CTN; ++ct)
        #pragma unroll
        for (int kt = 0; kt < KT; ++kt)
            bfr[ct][kt] = *(const short8*)(Wp + ((((ct0 + ct) * 8 + kt) * 64 + lane) << 3));
    float bv[CTN];
    #pragma unroll
    for (int ct = 0; ct < CTN; ++ct) bv[ct] = b[(ct0 + ct) * 16 + m];
    for (int rt = rt0; rt < ntiles; rt += rtstride) {
        floatx4 acc[CTN];
        #pragma unroll
        for (int ct = 0; ct < CTN; ++ct) acc[ct] = floatx4{0.f, 0.f, 0.f, 0.f};
        const float* hrow = h + (size_t)(rt * 16 + m) * K + quad * 8;
        #pragma unroll
        for (int kt = 0; kt < KT; ++kt) {
            floatx4 v0 = *(const floatx4*)(hrow + kt * 32);
            floatx4 v1 = *(const floatx4*)(hrow + kt * 32 + 4);
            short8 af;
            #pragma unroll
            for (int j = 0; j < 4; ++j) {
                af[j]     = (short)f2bfu(v0[j]);
                af[j + 4] = (short)f2bfu(v1[j]);
            }
            #pragma unroll
            for (int ct = 0; ct < CTN; ++ct)
                acc[ct] = __builtin_amdgcn_mfma_f32_16x16x32_bf16(af, bfr[ct][kt], acc[ct], 0, 0, 0);
        }
        #pragma unroll
        for (int ct = 0; ct < CTN; ++ct) {
            int col = (ct0 + ct) * 16 + m;
            #pragma unroll
            for (int reg = 0; reg < 4; ++reg) {
                int row = rt * 16 + quad * 4 + reg;
                out[(size_t)row * 64 + col] = f2bfu(fast_tanh(acc[ct][reg] + bv[ct]));
            }
        }
    }
}

// Fused proj: proj256 blocks FIRST (long-running -> start at t=0), then
// proj64. W-frag init is coalesced dwordx4 from prep's packed layout.
__global__ __launch_bounds__(256) void proj_fused(
        const float* __restrict__ hcon, const unsigned short* __restrict__ Wcp,
        const float* __restrict__ bc,
        const float* __restrict__ hun, const unsigned short* __restrict__ Wup,
        const float* __restrict__ bu,
        unsigned short* __restrict__ hc, unsigned short* __restrict__ hu,
        int t64, int t256, int g64, int g256) {
    int bid = blockIdx.x;
    int w = threadIdx.x >> 6;
    if (bid < g256) {
        int wid = bid * 4 + w;
        int half = wid & 1;                 // fixed per wave -> B-frags loaded once
        proj256_body(hun, Wup, bu, hu, half * 2, wid >> 1, g256 * 2, t256);
    } else {
        int wid = (bid - g256) * 4 + w;
        proj64_pair(hcon, Wcp, bc, hc, wid * 2);
    }
}

__device__ __forceinline__ void unp4(uint2 u, float f[4]) {
    f[0] = __uint_as_float(u.x << 16);
    f[1] = __uint_as_float(u.x & 0xffff0000u);
    f[2] = __uint_as_float(u.y << 16);
    f[3] = __uint_as_float(u.y & 0xffff0000u);
}

// One wave per sorted vi-segment. 4 edges x 16 lanes; each lane owns 4
// features (8B uint2 gathers). [R10 structure, byte-identical]
__global__ __launch_bounds__(256) void edge_kernel(
        const float* __restrict__ natt, const int* __restrict__ edges,
        const float* __restrict__ ey, const unsigned short* __restrict__ hc,
        const unsigned short* __restrict__ hu, const unsigned short* __restrict__ relt,
        const float* __restrict__ wsm, const float* __restrict__ fb,
        const float* __restrict__ outw, float* __restrict__ out, int N) {
    int lane = threadIdx.x & 63;
    int g = lane >> 4, sub = lane & 15;
    int l2 = lane >> 2;
    int s = blockIdx.x * 4 + (threadIdx.x >> 6);
    long base = (long)s * KPER;
    const int* eb = edges + base * 8;
    int eg = __builtin_amdgcn_readfirstlane(eb[0]);
    int vi = __builtin_amdgcn_readfirstlane(eb[1]);

    const int* ebg = eb + g * 8;
    int vjx[5], relx[5], evix[5], evjx[5];
    #pragma unroll
    for (int i = 0; i < 5; ++i) {
        vjx[i]  = ebg[i * 32 + 2];
        relx[i] = ebg[i * 32 + 3];
        evix[i] = ebg[i * 32 + 6];
        evjx[i] = ebg[i * 32 + 7];
    }
    uint2 G0[5], G2[5], G3[5], G4[5];
    #pragma unroll
    for (int i = 0; i < 5; ++i) {
        G0[i] = *(const uint2*)(hc   + (size_t)evix[i] * D + sub * 4);
        G2[i] = *(const uint2*)(relt + (size_t)relx[i] * D + sub * 4);
        G3[i] = *(const uint2*)(hc   + (size_t)evjx[i] * D + sub * 4);
        G4[i] = *(const uint2*)(hu   + (size_t)vjx[i]  * D + sub * 4);
    }
    uint2 F1u = *(const uint2*)(hu + (size_t)vi * D + sub * 4);
    float f1[4];
    unp4(F1u, f1);

    floatx4 wv[8];
    #pragma unroll
    for (int k = 0; k < 8; ++k) wv[k] = *(const floatx4*)(wsm + k * D + sub * 4);
    floatx4 fbv = *(const floatx4*)(fb + sub * 4);
    floatx4 owv = *(const floatx4*)(outw + sub * 4);
    float na = natt[(size_t)eg * N + vi];

    float myl = -INFINITY;
    #pragma unroll
    for (int i = 0; i < 5; ++i) {
        float F0[4], F2[4], F3[4], F4[4];
        unp4(G0[i], F0); unp4(G2[i], F2); unp4(G3[i], F3); unp4(G4[i], F4);
        float acc = 0.f;
        #pragma unroll
        for (int j = 0; j < 4; ++j) {
            float t1 = fmaf(F2[j], wv[1][j], wv[0][j]);
            float t2 = fmaf(F2[j], wv[5][j], wv[4][j]);
            float t3 = fmaf(F2[j], wv[3][j], wv[2][j]);
            float t4 = fmaf(F2[j], wv[7][j], wv[6][j]);
            float u = fmaf(F0[j], t1, f1[j] * t2);
            float v = fmaf(F0[j], t3, f1[j] * t4);
            float od = fmaf(F3[j], u, fmaf(F4[j], v, fbv[j]));
            acc = fmaf(fmaxf(od, 0.f), owv[j], acc);
        }
        float rs = row16_sum(acc);
        float tot = __shfl(rs, ((lane & 3) << 4) + 15);
        myl = (l2 == i) ? tot : myl;
    }
    float mx = wave_max_b(myl);
    float ex = __expf(myl - mx);
    float den = wave_sum_b(ex);
    if (lane < KPER) {
        int myvj = eb[lane * 8 + 2];
        float t = (ex / den) * na * ey[base + lane];
        atomicAdd(out + (size_t)eg * N + myvj, t);
    }
}

extern "C" void kernel_launch(void* const* d_in, const int* in_sizes, int n_in,
                              void* d_out, int out_size, void* d_ws, size_t ws_size,
                              hipStream_t stream) {
    const float* natt = (const float*)d_in[0];
    const int*   edges = (const int*)d_in[1];
    const float* ey   = (const float*)d_in[2];
    const float* hun  = (const float*)d_in[3];
    const float* hcon = (const float*)d_in[4];
    const float* Wc   = (const float*)d_in[5];
    const float* bc   = (const float*)d_in[6];
    const float* Wu   = (const float*)d_in[7];
    const float* bu   = (const float*)d_in[8];
    const float* relt = (const float*)d_in[9];
    const float* wsm  = (const float*)d_in[10];
    const float* fb   = (const float*)d_in[11];
    const float* outw = (const float*)d_in[12];
    float* out = (float*)d_out;

    int E    = in_sizes[2];          // 400000 edges
    int S    = E / KPER;             // 20000 sorted vi segments
    int nmem = in_sizes[4] / D;      // 131072 hidden_con rows
    int N    = in_sizes[3] / 256;    // 50000 nodes
    int nrel = in_sizes[9];          // 500*64

    int t64  = nmem / 16;            // 8192 row-tiles
    int t256 = N / 16;               // 3125 row-tiles
    int g64  = t64 / 8;              // 1024 blocks: 4 waves x 2 tiles each
    int g256 = 800;                  // 3200 half-waves, ~2 tiles each

    unsigned short* hc  = (unsigned short*)d_ws;
    unsigned short* hu  = hc + (size_t)nmem * D;
    unsigned short* rb  = hu + (size_t)N * D;
    unsigned short* Wcp = rb + nrel;
    unsigned short* Wup = Wcp + 4096;

    prep<<<64, 256, 0, stream>>>(Wc, Wu, relt, Wcp, Wup, rb, out, out_size, nrel);
    proj_fused<<<g256 + g64, 256, 0, stream>>>(hcon, Wcp, bc, hun, Wup, bu,
                                               hc, hu, t64, t256, g64, g256);
    edge_kernel<<<S / 4, 256, 0, stream>>>(natt, edges, ey, hc, hu, rb,
                                           wsm, fb, outw, out, N);
}